// Round 2
// baseline (98.065 us; speedup 1.0000x reference)
//
#include <hip/hip_runtime.h>
#include <cstdint>

// Problem constants (fixed by setup_inputs): (8, 4096, 6) fp32 both inputs.
#define NB 8
#define NP 4096
#define THREADS 256
#define Q 8                    // query points per thread (registers)
#define CHUNK (THREADS * Q)    // 2048 queries per block
#define NCHUNK (NP / CHUNK)    // 2
#define G 8                    // targets per group (max3-tree width)

// Per-pair inner math: s = q·t - 0.5|t|^2 (3 FMA, .w of LDS float4 holds the
// -0.5|t|^2 bias). Argmax tracked at GROUP granularity: per 8 targets a
// 9-value max tree (s0..s7 + bs_old, 4x v_max3) gives bs_new directly; the
// group won iff bs_new != bs_old (ties keep the earlier index -> first-index
// semantics). 24 FMA + 4 max3 + cmp + cndmask = 30 VALU / 8 pairs = 3.75/pair.
// Exact winning index recovered per query in the epilogue by recomputing the
// bit-identical fmaf chains from LDS (strict first-match within group).
// Block epilogue reconstructs d = |q|^2 - 2s and writes a packed partial
// (float bits of d chopped to 20 bits | 12-bit target idx) to a private
// slot -- no atomics. finish min-reduces partials.

template <int SEGV>
__global__ __launch_bounds__(THREADS) void chamfer_argmin(
    const float* __restrict__ xyz1, const float* __restrict__ xyz2,
    unsigned int* __restrict__ part, float* __restrict__ out)
{
    const int TSEG = NP / SEGV;
    __shared__ float4 tgt[NP / 16];          // max TSEG we instantiate (SEG>=16)

    unsigned int x = blockIdx.x;             // (((dir*8+b)*NCHUNK+chunk)*SEG+seg)
    if (x == 0 && threadIdx.x == 0) out[0] = 0.0f;  // replaces hipMemsetAsync
    int seg   = x & (SEGV - 1);
    int chunk = (x / SEGV) & (NCHUNK - 1);
    int b     = (x / (SEGV * NCHUNK)) & 7;
    int dir   = x / (SEGV * NCHUNK * 8);

    const float* qset = dir ? xyz2 : xyz1;
    const float* tset = dir ? xyz1 : xyz2;

    // Stage this segment's targets into LDS with the -0.5|t|^2 bias in .w.
    int tbase = seg * TSEG;
    for (int t0 = threadIdx.x; t0 < TSEG; t0 += THREADS) {
        const float* src = tset + ((size_t)b * NP + tbase + t0) * 6;
        float tx = src[0], ty = src[1], tz = src[2];
        tgt[t0] = make_float4(tx, ty, tz, -0.5f * (tx * tx + ty * ty + tz * tz));
    }
    __syncthreads();

    // Load Q query points into registers (stride THREADS between qi).
    float qx[Q], qy[Q], qz[Q], qq[Q], bs[Q];
    unsigned int bi[Q];                      // group-base index (segment-local)
    int qbase = chunk * CHUNK + threadIdx.x;
    #pragma unroll
    for (int i = 0; i < Q; ++i) {
        const float* src = qset + ((size_t)b * NP + qbase + i * THREADS) * 6;
        qx[i] = src[0]; qy[i] = src[1]; qz[i] = src[2];
        qq[i] = qx[i] * qx[i] + qy[i] * qy[i] + qz[i] * qz[i];
        bs[i] = -3.4e38f;
        bi[i] = 0u;
    }

    // Inner scan: LDS reads wave-uniform (broadcast), 3.75 VALU/pair.
    #pragma unroll 2
    for (int k = 0; k < TSEG; k += G) {
        float4 t0 = tgt[k + 0];
        float4 t1 = tgt[k + 1];
        float4 t2 = tgt[k + 2];
        float4 t3 = tgt[k + 3];
        float4 t4 = tgt[k + 4];
        float4 t5 = tgt[k + 5];
        float4 t6 = tgt[k + 6];
        float4 t7 = tgt[k + 7];
        #pragma unroll
        for (int i = 0; i < Q; ++i) {
            float s0 = fmaf(t0.x, qx[i], fmaf(t0.y, qy[i], fmaf(t0.z, qz[i], t0.w)));
            float s1 = fmaf(t1.x, qx[i], fmaf(t1.y, qy[i], fmaf(t1.z, qz[i], t1.w)));
            float s2 = fmaf(t2.x, qx[i], fmaf(t2.y, qy[i], fmaf(t2.z, qz[i], t2.w)));
            float s3 = fmaf(t3.x, qx[i], fmaf(t3.y, qy[i], fmaf(t3.z, qz[i], t3.w)));
            float s4 = fmaf(t4.x, qx[i], fmaf(t4.y, qy[i], fmaf(t4.z, qz[i], t4.w)));
            float s5 = fmaf(t5.x, qx[i], fmaf(t5.y, qy[i], fmaf(t5.z, qz[i], t5.w)));
            float s6 = fmaf(t6.x, qx[i], fmaf(t6.y, qy[i], fmaf(t6.z, qz[i], t6.w)));
            float s7 = fmaf(t7.x, qx[i], fmaf(t7.y, qy[i], fmaf(t7.z, qz[i], t7.w)));
            float old = bs[i];
            // 9-value max tree: 4x v_max3_f32 (nested fmaxf triples fuse).
            float m1 = fmaxf(fmaxf(s0, s1), s2);
            float m2 = fmaxf(fmaxf(s3, s4), s5);
            float m3 = fmaxf(fmaxf(s6, s7), old);
            float bn = fmaxf(fmaxf(m1, m2), m3);
            bs[i] = bn;
            if (bn != old) bi[i] = (unsigned int)k;   // won iff a strict > occurred
        }
    }

    // Disambiguate within the winning group (exact recompute, first match),
    // then write private partial slots: coalesced plain stores.
    unsigned int* slot =
        part + (((size_t)(dir * NB + b) * SEGV + seg) * NP) + qbase;
    #pragma unroll
    for (int i = 0; i < Q; ++i) {
        int k = (int)bi[i];
        unsigned int j  = (unsigned int)(tbase + k);
        unsigned int jj = j + 7;
        #pragma unroll
        for (int t = 6; t >= 0; --t) {
            float4 tv = tgt[k + t];
            float s = fmaf(tv.x, qx[i], fmaf(tv.y, qy[i], fmaf(tv.z, qz[i], tv.w)));
            jj = (s == bs[i]) ? j + (unsigned int)t : jj;  // descending -> first idx
        }
        float d = fmaxf(fmaf(-2.0f, bs[i], qq[i]), 0.0f);
        slot[i * THREADS] = (__float_as_uint(d) & 0xFFFFF000u) | jj;
    }
}

// finish: 4 threads per query (SEGV/4 segments each) -> 1024 blocks,
// 16 waves/CU (was 4): latency-bound gather gets real TLP. LDS min-combine,
// wave 0 does the normal distance + block reduction.
template <int SEGV>
__global__ __launch_bounds__(256) void chamfer_finish(
    const float* __restrict__ xyz1, const float* __restrict__ xyz2,
    const unsigned int* __restrict__ part, float* __restrict__ out)
{
    constexpr int SPS = SEGV / 4;                 // segments per sub-thread
    int ql  = threadIdx.x & 63;
    int sub = threadIdx.x >> 6;                   // 0..3
    int db  = blockIdx.x >> 6;                    // dir*8+b  (64 blocks per db)
    int q   = ((blockIdx.x & 63) << 6) + ql;
    int b   = db & 7;
    int dir = db >> 3;

    // Min-reduce packed partials (lanes contiguous in q -> coalesced 256B reads).
    const unsigned int* base = part + ((size_t)db * SEGV + sub * SPS) * NP + q;
    unsigned int p = 0xFFFFFFFFu;
    #pragma unroll
    for (int s = 0; s < SPS; ++s) p = min(p, base[(size_t)s * NP]);

    __shared__ unsigned int red[3][64];
    if (sub) { red[sub - 1][ql] = p; }
    __syncthreads();
    if (sub) return;
    p = min(min(p, red[0][ql]), min(red[1][ql], red[2][ql]));

    const float* qset = dir ? xyz2 : xyz1;
    const float* tset = dir ? xyz1 : xyz2;

    float dist = __uint_as_float(p & 0xFFFFF000u);
    int j = (int)(p & 0xFFFu);

    const float* nq = qset + ((size_t)b * NP + q) * 6 + 3;
    const float* nt = tset + ((size_t)b * NP + j) * 6 + 3;
    float ax = nq[0], ay = nq[1], az = nq[2];
    float bx = nt[0], by = nt[1], bz = nt[2];

    float na = fmaxf(sqrtf(ax * ax + ay * ay + az * az), 1e-12f);
    float nb = fmaxf(sqrtf(bx * bx + by * by + bz * bz), 1e-12f);
    float ra = 1.0f / na, rb = 1.0f / nb;
    float dx = ax * ra - bx * rb;
    float dy = ay * ra - by * rb;
    float dz = az * ra - bz * rb;
    float nd = dx * dx + dy * dy + dz * dz;

    // mean over 8*4096 for each of {dist, nd} per direction; sum of 4 means.
    float contrib = (dist + nd) * (1.0f / 32768.0f);

    for (int off = 32; off > 0; off >>= 1)
        contrib += __shfl_down(contrib, off, 64);
    if (ql == 0) atomicAdd(out, contrib);
}

extern "C" void kernel_launch(void* const* d_in, const int* in_sizes, int n_in,
                              void* d_out, int out_size, void* d_ws, size_t ws_size,
                              hipStream_t stream) {
    const float* xyz1 = (const float*)d_in[0];
    const float* xyz2 = (const float*)d_in[1];
    float* out = (float*)d_out;
    unsigned int* part = (unsigned int*)d_ws;

    size_t need32 = (size_t)2 * NB * 32 * NP * sizeof(unsigned int);  // 8 MB
    if (ws_size >= need32) {
        chamfer_argmin<32><<<2 * NB * NCHUNK * 32, THREADS, 0, stream>>>(xyz1, xyz2, part, out);
        chamfer_finish<32><<<16 * 64, 256, 0, stream>>>(xyz1, xyz2, part, out);
    } else {
        chamfer_argmin<16><<<2 * NB * NCHUNK * 16, THREADS, 0, stream>>>(xyz1, xyz2, part, out);
        chamfer_finish<16><<<16 * 64, 256, 0, stream>>>(xyz1, xyz2, part, out);
    }
}

// Round 3
// 86.451 us; speedup vs baseline: 1.1343x; 1.1343x over previous
//
#include <hip/hip_runtime.h>
#include <cstdint>

// Problem constants (fixed by setup_inputs): (8, 4096, 6) fp32 both inputs.
#define NB 8
#define NP 4096
#define THREADS 256
#define Q 8                    // query points per thread (registers)
#define CHUNK (THREADS * Q)    // 2048 queries per block
#define NCHUNK (NP / CHUNK)    // 2
#define G 4                    // targets per group (max-tree width)

// Per-pair inner math: s = q·t - 0.5|t|^2 (3 FMA, .w of LDS float4 holds the
// -0.5|t|^2 bias). Argmax tracked at GROUP granularity: per 4 targets a
// 5-value max tree folds the running best in via 2x v_max3
// (bn = max3(max3(s0,s1,s2), s3, old)); the group won iff bn != old (ties
// keep the earlier index -> first-index semantics).
// 12 FMA + 2 max3 + cmp + cndmask = 16 VALU / 4 pairs = 4.0/pair.
// Exact winning index recovered per query in the epilogue by recomputing the
// bit-identical fmaf chains from LDS (descending == chain -> first match).
// Block epilogue reconstructs d = |q|^2 - 2s and writes a packed partial
// (float bits of d chopped to 20 bits | 12-bit target idx) to a private
// slot -- no atomics in pass 1. finish min-reduces partials.

template <int SEGV>
__global__ __launch_bounds__(THREADS) void chamfer_argmin(
    const float* __restrict__ xyz1, const float* __restrict__ xyz2,
    unsigned int* __restrict__ part, float* __restrict__ out)
{
    const int TSEG = NP / SEGV;
    __shared__ float4 tgt[NP / 16];          // max TSEG we instantiate (SEG>=16)

    unsigned int x = blockIdx.x;             // (((dir*8+b)*NCHUNK+chunk)*SEG+seg)
    if (x == 0 && threadIdx.x == 0) out[0] = 0.0f;  // replaces hipMemsetAsync
    int seg   = x & (SEGV - 1);
    int chunk = (x / SEGV) & (NCHUNK - 1);
    int b     = (x / (SEGV * NCHUNK)) & 7;
    int dir   = x / (SEGV * NCHUNK * 8);

    const float* qset = dir ? xyz2 : xyz1;
    const float* tset = dir ? xyz1 : xyz2;

    // Stage this segment's targets into LDS with the -0.5|t|^2 bias in .w.
    int tbase = seg * TSEG;
    for (int t0 = threadIdx.x; t0 < TSEG; t0 += THREADS) {
        const float* src = tset + ((size_t)b * NP + tbase + t0) * 6;
        float tx = src[0], ty = src[1], tz = src[2];
        tgt[t0] = make_float4(tx, ty, tz, -0.5f * (tx * tx + ty * ty + tz * tz));
    }
    __syncthreads();

    // Load Q query points into registers (stride THREADS between qi).
    float qx[Q], qy[Q], qz[Q], qq[Q], bs[Q];
    unsigned int bi[Q];                      // group-base index (segment-local)
    int qbase = chunk * CHUNK + threadIdx.x;
    #pragma unroll
    for (int i = 0; i < Q; ++i) {
        const float* src = qset + ((size_t)b * NP + qbase + i * THREADS) * 6;
        qx[i] = src[0]; qy[i] = src[1]; qz[i] = src[2];
        qq[i] = qx[i] * qx[i] + qy[i] * qy[i] + qz[i] * qz[i];
        bs[i] = -3.4e38f;
        bi[i] = 0u;
    }

    // Inner scan: LDS reads wave-uniform (broadcast), 4.0 VALU/pair.
    #pragma unroll 2
    for (int k = 0; k < TSEG; k += G) {
        float4 t0 = tgt[k + 0];
        float4 t1 = tgt[k + 1];
        float4 t2 = tgt[k + 2];
        float4 t3 = tgt[k + 3];
        #pragma unroll
        for (int i = 0; i < Q; ++i) {
            float s0 = fmaf(t0.x, qx[i], fmaf(t0.y, qy[i], fmaf(t0.z, qz[i], t0.w)));
            float s1 = fmaf(t1.x, qx[i], fmaf(t1.y, qy[i], fmaf(t1.z, qz[i], t1.w)));
            float s2 = fmaf(t2.x, qx[i], fmaf(t2.y, qy[i], fmaf(t2.z, qz[i], t2.w)));
            float s3 = fmaf(t3.x, qx[i], fmaf(t3.y, qy[i], fmaf(t3.z, qz[i], t3.w)));
            float old = bs[i];
            // 5-value max tree: 2x v_max3_f32 (nested fmaxf triples fuse).
            float bn = fmaxf(fmaxf(fmaxf(fmaxf(s0, s1), s2), s3), old);
            bs[i] = bn;
            if (bn != old) bi[i] = (unsigned int)k;   // won iff a strict > occurred
        }
    }

    // Disambiguate within the winning group (exact recompute, first match),
    // then write private partial slots: coalesced plain stores.
    unsigned int* slot =
        part + (((size_t)(dir * NB + b) * SEGV + seg) * NP) + qbase;
    #pragma unroll
    for (int i = 0; i < Q; ++i) {
        int k = (int)bi[i];
        float4 t0 = tgt[k + 0];
        float4 t1 = tgt[k + 1];
        float4 t2 = tgt[k + 2];
        float s0 = fmaf(t0.x, qx[i], fmaf(t0.y, qy[i], fmaf(t0.z, qz[i], t0.w)));
        float s1 = fmaf(t1.x, qx[i], fmaf(t1.y, qy[i], fmaf(t1.z, qz[i], t1.w)));
        float s2 = fmaf(t2.x, qx[i], fmaf(t2.y, qy[i], fmaf(t2.z, qz[i], t2.w)));
        unsigned int j  = (unsigned int)(tbase + k);
        unsigned int jj = j + 3;
        jj = (s2 == bs[i]) ? j + 2 : jj;     // descending chain -> first index
        jj = (s1 == bs[i]) ? j + 1 : jj;
        jj = (s0 == bs[i]) ? j     : jj;
        float d = fmaxf(fmaf(-2.0f, bs[i], qq[i]), 0.0f);
        slot[i * THREADS] = (__float_as_uint(d) & 0xFFFFF000u) | jj;
    }
}

// finish: 64 blocks x 1024 threads, 1 query/thread (same mapping/coalescing as
// the proven 256x256 version) but only ONE atomicAdd per block -> 64 total
// same-address atomics (was 256). Per-wave shfl reduce -> LDS[16] -> thread 0.
template <int SEGV>
__global__ __launch_bounds__(1024) void chamfer_finish(
    const float* __restrict__ xyz1, const float* __restrict__ xyz2,
    const unsigned int* __restrict__ part, float* __restrict__ out)
{
    int gid = blockIdx.x * 1024 + threadIdx.x;   // 0 .. 2*NB*NP-1
    int q   = gid & (NP - 1);
    int db  = gid >> 12;                          // dir*8+b
    int b   = db & 7;
    int dir = db >> 3;

    // Min-reduce packed partials across segments (lanes contiguous in q ->
    // each iteration is a coalesced 256B wave read, L2/L3-resident).
    const unsigned int* base = part + ((size_t)db * SEGV) * NP + q;
    unsigned int p = 0xFFFFFFFFu;
    #pragma unroll
    for (int s = 0; s < SEGV; ++s) p = min(p, base[(size_t)s * NP]);

    const float* qset = dir ? xyz2 : xyz1;
    const float* tset = dir ? xyz1 : xyz2;

    float dist = __uint_as_float(p & 0xFFFFF000u);
    int j = (int)(p & 0xFFFu);

    const float* nq = qset + ((size_t)b * NP + q) * 6 + 3;
    const float* nt = tset + ((size_t)b * NP + j) * 6 + 3;
    float ax = nq[0], ay = nq[1], az = nq[2];
    float bx = nt[0], by = nt[1], bz = nt[2];

    float na = fmaxf(sqrtf(ax * ax + ay * ay + az * az), 1e-12f);
    float nb = fmaxf(sqrtf(bx * bx + by * by + bz * bz), 1e-12f);
    float ra = 1.0f / na, rb = 1.0f / nb;
    float dx = ax * ra - bx * rb;
    float dy = ay * ra - by * rb;
    float dz = az * ra - bz * rb;
    float nd = dx * dx + dy * dy + dz * dz;

    // mean over 8*4096 for each of {dist, nd} per direction; sum of 4 means.
    float contrib = (dist + nd) * (1.0f / 32768.0f);

    for (int off = 32; off > 0; off >>= 1)
        contrib += __shfl_down(contrib, off, 64);
    __shared__ float wsum[16];
    if ((threadIdx.x & 63) == 0) wsum[threadIdx.x >> 6] = contrib;
    __syncthreads();
    if (threadIdx.x == 0) {
        float s = 0.0f;
        #pragma unroll
        for (int w = 0; w < 16; ++w) s += wsum[w];
        atomicAdd(out, s);
    }
}

extern "C" void kernel_launch(void* const* d_in, const int* in_sizes, int n_in,
                              void* d_out, int out_size, void* d_ws, size_t ws_size,
                              hipStream_t stream) {
    const float* xyz1 = (const float*)d_in[0];
    const float* xyz2 = (const float*)d_in[1];
    float* out = (float*)d_out;
    unsigned int* part = (unsigned int*)d_ws;

    size_t need32 = (size_t)2 * NB * 32 * NP * sizeof(unsigned int);  // 8 MB
    if (ws_size >= need32) {
        chamfer_argmin<32><<<2 * NB * NCHUNK * 32, THREADS, 0, stream>>>(xyz1, xyz2, part, out);
        chamfer_finish<32><<<(2 * NB * NP) / 1024, 1024, 0, stream>>>(xyz1, xyz2, part, out);
    } else {
        chamfer_argmin<16><<<2 * NB * NCHUNK * 16, THREADS, 0, stream>>>(xyz1, xyz2, part, out);
        chamfer_finish<16><<<(2 * NB * NP) / 1024, 1024, 0, stream>>>(xyz1, xyz2, part, out);
    }
}